// Round 3
// baseline (3105.375 us; speedup 1.0000x reference)
//
#include <hip/hip_runtime.h>
#include <hip/hip_bf16.h>
#include <math.h>

// MoE-GPT forward, f32 correctness-first baseline.
// L=2 C=768 H=12 HD=64 E=8 K=2 F=3072 V=50257 T=1024, B=1.

#define TT 1024
#define CC 768
#define HH 12
#define HD 64
#define LL 2
#define EE 8
#define KK2 2
#define FF 3072
#define VV 50257
#define NPAIR (TT * KK2)

// ---------------------------------------------------------------- utilities
__device__ __forceinline__ float gelu_f(float x) {
    return 0.5f * x * (1.f + erff(x * 0.70710678118654752f));
}

// ---------------------------------------------------------------- embed
__global__ void embed_kernel(const int* __restrict__ idx, const float* __restrict__ wte,
                             const float* __restrict__ wpe, float* __restrict__ x) {
    int i = blockIdx.x * 256 + threadIdx.x;
    if (i >= TT * CC) return;
    int t = i / CC, c = i % CC;
    x[i] = wte[(size_t)idx[t] * CC + c] + wpe[i];
}

// ---------------------------------------------------------------- layernorm (block per row)
__global__ __launch_bounds__(256) void ln_kernel(const float* __restrict__ X,
                                                 const float* __restrict__ g,
                                                 float* __restrict__ Y, int nrows) {
    int r = blockIdx.x;
    if (r >= nrows) return;
    const float* x = X + (size_t)r * CC;
    float* y = Y + (size_t)r * CC;
    int tid = threadIdx.x;
    float v[3], s = 0.f, s2 = 0.f;
#pragma unroll
    for (int i = 0; i < 3; i++) {
        float t = x[tid + i * 256];
        v[i] = t; s += t; s2 += t * t;
    }
    for (int o = 32; o; o >>= 1) { s += __shfl_xor(s, o); s2 += __shfl_xor(s2, o); }
    __shared__ float rs[4], rs2[4];
    int w = tid >> 6;
    if ((tid & 63) == 0) { rs[w] = s; rs2[w] = s2; }
    __syncthreads();
    s = rs[0] + rs[1] + rs[2] + rs[3];
    s2 = rs2[0] + rs2[1] + rs2[2] + rs2[3];
    float mu = s * (1.f / CC);
    float var = s2 * (1.f / CC) - mu * mu;
    float inv = rsqrtf(var + 1e-5f);
#pragma unroll
    for (int i = 0; i < 3; i++) {
        int c = tid + i * 256;
        y[c] = (v[i] - mu) * inv * g[c];
    }
}

// ---------------------------------------------------------------- generic NT GEMM
// Out[moff+m, n] = act( sum_k A[row(m), k] * W[e*N + n, k] ) (+ residual)
// ACT: 0 none, 1 gelu.  GATHER: A row = ptok[moff+m].  RESID: add Rbase.
#define BM 128
#define BN 128
#define BKK 16

template <int ACT, int GATHER, int RESID>
__global__ __launch_bounds__(256) void gemm_nt(const float* __restrict__ Abase, int lda,
                                               const float* __restrict__ Wbase,
                                               float* __restrict__ Obase, int ldo,
                                               const float* __restrict__ Rbase,
                                               const int* __restrict__ ptok,
                                               const int* __restrict__ offs,
                                               const int* __restrict__ counts,
                                               int Mfull, int N, int Kd) {
    int e = blockIdx.z;
    int cnt, moff;
    if (counts) { cnt = counts[e]; moff = offs[e]; }
    else        { cnt = Mfull;     moff = 0; }
    int m0 = blockIdx.y * BM;
    if (m0 >= cnt) return;
    int n0 = blockIdx.x * BN;
    const float* W = Wbase + (size_t)e * N * Kd;

    __shared__ float As[BKK][BM];
    __shared__ float Bs[BKK][BN];

    int tid = threadIdx.x;
    int srow = tid >> 1;            // 0..127 staging row
    int sseg = (tid & 1) * 8;       // 0 or 8 (k-offset)

    int amr = m0 + srow;
    if (amr >= cnt) amr = cnt - 1;  // clamp (outputs not stored for those rows)
    int agr = moff + amr;
    int asrc = GATHER ? ptok[agr] : agr;
    const float* aptr = Abase + (size_t)asrc * lda + sseg;
    const float* bptr = W + (size_t)(n0 + srow) * Kd + sseg;

    float acc[8][8] = {};
    int ar0 = (tid >> 4) * 8;
    int bc0 = (tid & 15) * 8;

    for (int k0 = 0; k0 < Kd; k0 += BKK) {
        float4 a0 = *(const float4*)(aptr + k0);
        float4 a1 = *(const float4*)(aptr + k0 + 4);
        float4 b0 = *(const float4*)(bptr + k0);
        float4 b1 = *(const float4*)(bptr + k0 + 4);
        __syncthreads();
        As[sseg + 0][srow] = a0.x; As[sseg + 1][srow] = a0.y;
        As[sseg + 2][srow] = a0.z; As[sseg + 3][srow] = a0.w;
        As[sseg + 4][srow] = a1.x; As[sseg + 5][srow] = a1.y;
        As[sseg + 6][srow] = a1.z; As[sseg + 7][srow] = a1.w;
        Bs[sseg + 0][srow] = b0.x; Bs[sseg + 1][srow] = b0.y;
        Bs[sseg + 2][srow] = b0.z; Bs[sseg + 3][srow] = b0.w;
        Bs[sseg + 4][srow] = b1.x; Bs[sseg + 5][srow] = b1.y;
        Bs[sseg + 6][srow] = b1.z; Bs[sseg + 7][srow] = b1.w;
        __syncthreads();
#pragma unroll
        for (int kk = 0; kk < BKK; kk++) {
            float4 av0 = *(const float4*)&As[kk][ar0];
            float4 av1 = *(const float4*)&As[kk][ar0 + 4];
            float4 bv0 = *(const float4*)&Bs[kk][bc0];
            float4 bv1 = *(const float4*)&Bs[kk][bc0 + 4];
            float a[8] = {av0.x, av0.y, av0.z, av0.w, av1.x, av1.y, av1.z, av1.w};
            float b[8] = {bv0.x, bv0.y, bv0.z, bv0.w, bv1.x, bv1.y, bv1.z, bv1.w};
#pragma unroll
            for (int i = 0; i < 8; i++)
#pragma unroll
                for (int j = 0; j < 8; j++) acc[i][j] += a[i] * b[j];
        }
    }

#pragma unroll
    for (int i = 0; i < 8; i++) {
        int lm = m0 + ar0 + i;
        if (lm >= cnt) break;
        size_t orow = (size_t)(moff + lm) * ldo;
#pragma unroll
        for (int j = 0; j < 8; j++) {
            float v = acc[i][j];
            if (ACT == 1) v = gelu_f(v);
            int col = n0 + bc0 + j;
            float r = RESID ? Rbase[orow + col] : 0.f;
            Obase[orow + col] = r + v;
        }
    }
}

// ---------------------------------------------------------------- fused causal attention
// block per (q,h); scores in LDS; atty[t, h*64+d]
__global__ __launch_bounds__(256) void attn_kernel(const float* __restrict__ qkv,
                                                   float* __restrict__ atty) {
    int q = blockIdx.x, h = blockIdx.y;
    int tid = threadIdx.x;
    __shared__ float sc[TT];
    __shared__ float qv[HD];
    __shared__ float redmax[4], redsum[4];
    __shared__ float part[4][HD];

    if (tid < HD) qv[tid] = qkv[(size_t)q * (3 * CC) + h * HD + tid];
    __syncthreads();

    int nk = q + 1;
    float lmax = -1e30f;
    for (int k = tid; k < nk; k += 256) {
        const float* kr = qkv + (size_t)k * (3 * CC) + CC + h * HD;
        float a = 0.f;
#pragma unroll
        for (int d = 0; d < HD; d++) a += qv[d] * kr[d];
        a *= 0.125f;  // 1/sqrt(64)
        sc[k] = a;
        lmax = fmaxf(lmax, a);
    }
    for (int o = 32; o; o >>= 1) lmax = fmaxf(lmax, __shfl_xor(lmax, o));
    if ((tid & 63) == 0) redmax[tid >> 6] = lmax;
    __syncthreads();
    float gmax = fmaxf(fmaxf(redmax[0], redmax[1]), fmaxf(redmax[2], redmax[3]));
    __syncthreads();

    float lsum = 0.f;
    for (int k = tid; k < nk; k += 256) {
        float p = expf(sc[k] - gmax);
        sc[k] = p;
        lsum += p;
    }
    for (int o = 32; o; o >>= 1) lsum += __shfl_xor(lsum, o);
    if ((tid & 63) == 0) redsum[tid >> 6] = lsum;
    __syncthreads();  // also makes all sc[] writes visible
    float inv = 1.f / (redsum[0] + redsum[1] + redsum[2] + redsum[3]);

    int d = tid & 63, ch = tid >> 6;
    float acc = 0.f;
    for (int k = ch; k < nk; k += 4)
        acc += sc[k] * qkv[(size_t)k * (3 * CC) + 2 * CC + h * HD + d];
    part[ch][d] = acc;
    __syncthreads();
    if (tid < HD) {
        float o = (part[0][tid] + part[1][tid] + part[2][tid] + part[3][tid]) * inv;
        atty[(size_t)q * CC + h * HD + tid] = o;
    }
}

// ---------------------------------------------------------------- MoE gating / routing
__global__ void zero_counts(int* counts) {
    if (threadIdx.x < EE) counts[threadIdx.x] = 0;
}

__global__ __launch_bounds__(64) void gate_kernel(const float* __restrict__ ln,
                                                  const float* __restrict__ gw,
                                                  int* __restrict__ topi, float* __restrict__ tsc,
                                                  int* __restrict__ counts) {
    int n = blockIdx.x;
    int lane = threadIdx.x;
    const float* xr = ln + (size_t)n * CC;
    float lg[EE];
#pragma unroll
    for (int e = 0; e < EE; e++) {
        const float* g = gw + e * CC;
        float p = 0.f;
#pragma unroll
        for (int i = 0; i < CC / 64; i++) {
            int c = i * 64 + lane;
            p += xr[c] * g[c];
        }
        for (int o = 32; o; o >>= 1) p += __shfl_xor(p, o);
        lg[e] = p;
    }
    if (lane == 0) {
        int b0 = 0; float v0 = lg[0];
        for (int e = 1; e < EE; e++) if (lg[e] > v0) { v0 = lg[e]; b0 = e; }
        int b1 = -1; float v1 = -1e30f;
        for (int e = 0; e < EE; e++) if (e != b0 && lg[e] > v1) { v1 = lg[e]; b1 = e; }
        float e1 = expf(v1 - v0);
        float den = 1.f + e1;
        topi[n * 2] = b0; topi[n * 2 + 1] = b1;
        tsc[n * 2] = 1.f / den; tsc[n * 2 + 1] = e1 / den;
        atomicAdd(&counts[b0], 1);
        atomicAdd(&counts[b1], 1);
    }
}

__global__ void offsets_kernel(const int* __restrict__ counts, int* __restrict__ offs,
                               int* __restrict__ cursor) {
    if (threadIdx.x == 0) {
        int o = 0;
        for (int e = 0; e < EE; e++) { offs[e] = o; o += counts[e]; cursor[e] = 0; }
    }
}

__global__ void scatter_kernel(const int* __restrict__ topi, int* __restrict__ cursor,
                               const int* __restrict__ offs, int* __restrict__ ptok,
                               int* __restrict__ ppos) {
    int n = blockIdx.x * 256 + threadIdx.x;
    if (n >= TT) return;
    for (int k = 0; k < KK2; k++) {
        int e = topi[n * 2 + k];
        int slot = atomicAdd(&cursor[e], 1);
        int p = offs[e] + slot;
        ptok[p] = n;
        ppos[n * 2 + k] = p;
    }
}

__global__ void combine_kernel(const float* __restrict__ ybuf, const float* __restrict__ tsc,
                               const int* __restrict__ ppos, float* __restrict__ x) {
    int i = blockIdx.x * 256 + threadIdx.x;
    if (i >= TT * CC) return;
    int n = i / CC, c = i % CC;
    float v = tsc[n * 2] * ybuf[(size_t)ppos[n * 2] * CC + c] +
              tsc[n * 2 + 1] * ybuf[(size_t)ppos[n * 2 + 1] * CC + c];
    x[i] += v;
}

// ---------------------------------------------------------------- lm head (wave per vocab row)
__global__ __launch_bounds__(256) void lm_head_kernel(const float* __restrict__ xr,
                                                      const float* __restrict__ wte,
                                                      float* __restrict__ out) {
    int row = blockIdx.x * 4 + (threadIdx.x >> 6);
    if (row >= VV) return;
    int lane = threadIdx.x & 63;
    const float* w = wte + (size_t)row * CC;
    float acc = 0.f;
#pragma unroll
    for (int i = 0; i < CC / 64; i++) {
        int c = i * 64 + lane;
        acc += xr[c] * w[c];
    }
    for (int o = 32; o; o >>= 1) acc += __shfl_xor(acc, o);
    if (lane == 0) out[row] = acc;
}

// ---------------------------------------------------------------- launch
extern "C" void kernel_launch(void* const* d_in, const int* in_sizes, int n_in,
                              void* d_out, int out_size, void* d_ws, size_t ws_size,
                              hipStream_t stream) {
    const int*   idx    = (const int*)d_in[0];
    const float* wte    = (const float*)d_in[1];
    const float* wpe    = (const float*)d_in[2];
    const float* ln1_g  = (const float*)d_in[3];
    const float* qkv_w  = (const float*)d_in[4];
    const float* proj_w = (const float*)d_in[5];
    const float* ln2_g  = (const float*)d_in[6];
    const float* gate_w = (const float*)d_in[7];
    const float* w1     = (const float*)d_in[8];
    const float* w2     = (const float*)d_in[9];
    const float* lnf_g  = (const float*)d_in[10];
    float* out = (float*)d_out;

    float* ws   = (float*)d_ws;
    float* x    = ws;                       // T*C
    float* ln   = x + TT * CC;              // T*C
    float* qkv  = ln + TT * CC;             // T*3C
    float* atty = qkv + (size_t)TT * 3 * CC;  // T*C
    float* hbuf = atty + TT * CC;           // NPAIR*F
    float* ybuf = hbuf + (size_t)NPAIR * FF;  // NPAIR*C
    float* tsc  = ybuf + (size_t)NPAIR * CC;  // T*K
    int* ibase  = (int*)(tsc + TT * KK2);
    int* topi   = ibase;                    // T*K
    int* ppos   = topi + TT * KK2;          // T*K
    int* ptok   = ppos + TT * KK2;          // NPAIR
    int* counts = ptok + NPAIR;             // E
    int* offs   = counts + EE;              // E
    int* cursor = offs + EE;                // E

    embed_kernel<<<(TT * CC + 255) / 256, 256, 0, stream>>>(idx, wte, wpe, x);

    for (int l = 0; l < LL; l++) {
        // attention block
        ln_kernel<<<TT, 256, 0, stream>>>(x, ln1_g + l * CC, ln, TT);
        gemm_nt<0, 0, 0><<<dim3(3 * CC / BN, TT / BM, 1), 256, 0, stream>>>(
            ln, CC, qkv_w + (size_t)l * 3 * CC * CC, qkv, 3 * CC,
            nullptr, nullptr, nullptr, nullptr, TT, 3 * CC, CC);
        attn_kernel<<<dim3(TT, HH), 256, 0, stream>>>(qkv, atty);
        gemm_nt<0, 0, 1><<<dim3(CC / BN, TT / BM, 1), 256, 0, stream>>>(
            atty, CC, proj_w + (size_t)l * CC * CC, x, CC,
            x, nullptr, nullptr, nullptr, TT, CC, CC);

        // MoE block
        ln_kernel<<<TT, 256, 0, stream>>>(x, ln2_g + l * CC, ln, TT);
        zero_counts<<<1, 32, 0, stream>>>(counts);
        gate_kernel<<<TT, 64, 0, stream>>>(ln, gate_w + (size_t)l * EE * CC, topi, tsc, counts);
        offsets_kernel<<<1, 32, 0, stream>>>(counts, offs, cursor);
        scatter_kernel<<<(TT + 255) / 256, 256, 0, stream>>>(topi, cursor, offs, ptok, ppos);
        gemm_nt<1, 1, 0><<<dim3(FF / BN, TT / BM, EE), 256, 0, stream>>>(
            ln, CC, w1 + (size_t)l * EE * FF * CC, hbuf, FF,
            nullptr, ptok, offs, counts, 0, FF, CC);
        gemm_nt<0, 0, 0><<<dim3(CC / BN, TT / BM, EE), 256, 0, stream>>>(
            hbuf, FF, w2 + (size_t)l * EE * CC * FF, ybuf, CC,
            nullptr, nullptr, offs, counts, 0, CC, FF);
        combine_kernel<<<(TT * CC + 255) / 256, 256, 0, stream>>>(ybuf, tsc, ppos, x);
    }

    // final LN (only the last position matters for the output)
    ln_kernel<<<1, 256, 0, stream>>>(x + (size_t)(TT - 1) * CC, lnf_g, ln, 1);
    lm_head_kernel<<<(VV + 3) / 4, 256, 0, stream>>>(ln, wte, out);
}

// Round 4
// 1756.567 us; speedup vs baseline: 1.7679x; 1.7679x over previous
//
#include <hip/hip_runtime.h>
#include <hip/hip_bf16.h>
#include <math.h>

// MoE-GPT forward. Round 3: bf16-MFMA GEMMs (QKV/proj/w1/w2), f32 elsewhere.
// L=2 C=768 H=12 HD=64 E=8 K=2 F=3072 V=50257 T=1024, B=1.

#define TT 1024
#define CC 768
#define HH 12
#define HD 64
#define LL 2
#define EE 8
#define KK2 2
#define FF 3072
#define VV 50257
#define NPAIR (TT * KK2)

typedef __attribute__((ext_vector_type(8))) short mfrag;  // 8 bf16 in 4 VGPRs
typedef __attribute__((ext_vector_type(4))) float facc;   // 4 f32 accum

// ---------------------------------------------------------------- utilities
__device__ __forceinline__ float gelu_f(float x) {
    return 0.5f * x * (1.f + erff(x * 0.70710678118654752f));
}

__device__ __forceinline__ unsigned short f2bf(float f) {  // RNE f32 -> bf16 bits
    unsigned u = __float_as_uint(f);
    u += 0x7fffu + ((u >> 16) & 1u);
    return (unsigned short)(u >> 16);
}

// ---------------------------------------------------------------- embed
__global__ void embed_kernel(const int* __restrict__ idx, const float* __restrict__ wte,
                             const float* __restrict__ wpe, float* __restrict__ x) {
    int i = blockIdx.x * 256 + threadIdx.x;
    if (i >= TT * CC) return;
    int t = i / CC, c = i % CC;
    x[i] = wte[(size_t)idx[t] * CC + c] + wpe[i];
}

// ---------------------------------------------------------------- layernorm (block per row)
__global__ __launch_bounds__(256) void ln_kernel(const float* __restrict__ X,
                                                 const float* __restrict__ g,
                                                 float* __restrict__ Y, int nrows) {
    int r = blockIdx.x;
    if (r >= nrows) return;
    const float* x = X + (size_t)r * CC;
    float* y = Y + (size_t)r * CC;
    int tid = threadIdx.x;
    float v[3], s = 0.f, s2 = 0.f;
#pragma unroll
    for (int i = 0; i < 3; i++) {
        float t = x[tid + i * 256];
        v[i] = t; s += t; s2 += t * t;
    }
    for (int o = 32; o; o >>= 1) { s += __shfl_xor(s, o); s2 += __shfl_xor(s2, o); }
    __shared__ float rs[4], rs2[4];
    int w = tid >> 6;
    if ((tid & 63) == 0) { rs[w] = s; rs2[w] = s2; }
    __syncthreads();
    s = rs[0] + rs[1] + rs[2] + rs[3];
    s2 = rs2[0] + rs2[1] + rs2[2] + rs2[3];
    float mu = s * (1.f / CC);
    float var = s2 * (1.f / CC) - mu * mu;
    float inv = rsqrtf(var + 1e-5f);
#pragma unroll
    for (int i = 0; i < 3; i++) {
        int c = tid + i * 256;
        y[c] = (v[i] - mu) * inv * g[c];
    }
}

// ---------------------------------------------------------------- bf16 MFMA NT GEMM
// Out[moff+m, n] = act( sum_k A[row(m), k] * W[e*N + n, k] ) (+ residual)
// A, W are f32 in HBM; converted to bf16 during LDS staging; f32 accum via MFMA.
// Tile 128x128, BK=32, 256 threads = 4 waves (2x2), 4x4 16x16x32 frags per wave.
// LDS row stride 40 ushorts (80B = 20 banks) -> ~2-way conflicts (free, m136).
template <int ACT, int GATHER, int RESID>
__global__ __launch_bounds__(256) void gemm_mfma(const float* __restrict__ Abase, int lda,
                                                 const float* __restrict__ Wbase,
                                                 float* __restrict__ Obase, int ldo,
                                                 const float* __restrict__ Rbase,
                                                 const int* __restrict__ ptok,
                                                 const int* __restrict__ offs,
                                                 const int* __restrict__ counts,
                                                 int Mfull, int N, int Kd) {
    int e = blockIdx.z;
    int cnt, moff;
    if (counts) { cnt = counts[e]; moff = offs[e]; }
    else        { cnt = Mfull;     moff = 0; }
    int m0 = blockIdx.y * 128;
    if (m0 >= cnt) return;
    int n0 = blockIdx.x * 128;
    const float* W = Wbase + (size_t)e * N * Kd;

    __shared__ unsigned short As[128 * 40];  // 10 KB
    __shared__ unsigned short Bs[128 * 40];  // 10 KB

    int tid = threadIdx.x;
    // staging: thread t covers rows (t>>3)+{0,32,64,96}, k-cols (t&7)*4..+3
    int srow = tid >> 3;
    int skp  = (tid & 7) * 4;

    const float* arow[4];
    const float* brow[4];
#pragma unroll
    for (int j = 0; j < 4; j++) {
        int mr = m0 + srow + j * 32;
        if (mr >= cnt) mr = cnt - 1;                      // clamp; stores masked later
        int asrc = GATHER ? ptok[moff + mr] : (moff + mr);
        arow[j] = Abase + (size_t)asrc * lda + skp;
        brow[j] = W + (size_t)(n0 + srow + j * 32) * Kd + skp;
    }

    int wid = tid >> 6, lane = tid & 63;
    int wr = (wid >> 1) * 64;       // wave row base in tile
    int wc = (wid & 1) * 64;        // wave col base in tile
    int lrow = lane & 15;           // frag row (A) / col (B)
    int lkb  = (lane >> 4) * 8;     // k-base within BK=32

    facc acc[4][4];
#pragma unroll
    for (int m = 0; m < 4; m++)
#pragma unroll
        for (int n = 0; n < 4; n++) acc[m][n] = (facc){0.f, 0.f, 0.f, 0.f};

    for (int k0 = 0; k0 < Kd; k0 += 32) {
        float4 av[4], bv[4];
#pragma unroll
        for (int j = 0; j < 4; j++) {
            av[j] = *(const float4*)(arow[j] + k0);
            bv[j] = *(const float4*)(brow[j] + k0);
        }
        __syncthreads();  // previous compute done before overwriting LDS
#pragma unroll
        for (int j = 0; j < 4; j++) {
            int r = srow + j * 32;
            union { unsigned short u[4]; uint2 v; } pa, pb;
            pa.u[0] = f2bf(av[j].x); pa.u[1] = f2bf(av[j].y);
            pa.u[2] = f2bf(av[j].z); pa.u[3] = f2bf(av[j].w);
            pb.u[0] = f2bf(bv[j].x); pb.u[1] = f2bf(bv[j].y);
            pb.u[2] = f2bf(bv[j].z); pb.u[3] = f2bf(bv[j].w);
            *(uint2*)&As[r * 40 + skp] = pa.v;
            *(uint2*)&Bs[r * 40 + skp] = pb.v;
        }
        __syncthreads();
        mfrag af[4], bf[4];
#pragma unroll
        for (int m = 0; m < 4; m++)
            af[m] = *(const mfrag*)&As[(wr + m * 16 + lrow) * 40 + lkb];
#pragma unroll
        for (int n = 0; n < 4; n++)
            bf[n] = *(const mfrag*)&Bs[(wc + n * 16 + lrow) * 40 + lkb];
#pragma unroll
        for (int m = 0; m < 4; m++)
#pragma unroll
            for (int n = 0; n < 4; n++)
                acc[m][n] = __builtin_amdgcn_mfma_f32_16x16x32_bf16(af[m], bf[n], acc[m][n], 0, 0, 0);
    }

    // epilogue: C/D layout col=lane&15, row=(lane>>4)*4+reg (m89-verified)
    int crow4 = (lane >> 4) * 4;
    int ccol  = lane & 15;
#pragma unroll
    for (int m = 0; m < 4; m++) {
#pragma unroll
        for (int reg = 0; reg < 4; reg++) {
            int lm = m0 + wr + m * 16 + crow4 + reg;
            if (lm >= cnt) continue;
            size_t orow = (size_t)(moff + lm) * ldo;
#pragma unroll
            for (int n = 0; n < 4; n++) {
                int col = n0 + wc + n * 16 + ccol;
                float v = acc[m][n][reg];
                if (ACT == 1) v = gelu_f(v);
                float r = RESID ? Rbase[orow + col] : 0.f;
                Obase[orow + col] = r + v;
            }
        }
    }
}

// ---------------------------------------------------------------- fused causal attention
__global__ __launch_bounds__(256) void attn_kernel(const float* __restrict__ qkv,
                                                   float* __restrict__ atty) {
    int q = blockIdx.x, h = blockIdx.y;
    int tid = threadIdx.x;
    __shared__ float sc[TT];
    __shared__ float qv[HD];
    __shared__ float redmax[4], redsum[4];
    __shared__ float part[4][HD];

    if (tid < HD) qv[tid] = qkv[(size_t)q * (3 * CC) + h * HD + tid];
    __syncthreads();

    int nk = q + 1;
    float lmax = -1e30f;
    for (int k = tid; k < nk; k += 256) {
        const float* kr = qkv + (size_t)k * (3 * CC) + CC + h * HD;
        float a = 0.f;
#pragma unroll
        for (int d = 0; d < HD; d++) a += qv[d] * kr[d];
        a *= 0.125f;
        sc[k] = a;
        lmax = fmaxf(lmax, a);
    }
    for (int o = 32; o; o >>= 1) lmax = fmaxf(lmax, __shfl_xor(lmax, o));
    if ((tid & 63) == 0) redmax[tid >> 6] = lmax;
    __syncthreads();
    float gmax = fmaxf(fmaxf(redmax[0], redmax[1]), fmaxf(redmax[2], redmax[3]));
    __syncthreads();

    float lsum = 0.f;
    for (int k = tid; k < nk; k += 256) {
        float p = expf(sc[k] - gmax);
        sc[k] = p;
        lsum += p;
    }
    for (int o = 32; o; o >>= 1) lsum += __shfl_xor(lsum, o);
    if ((tid & 63) == 0) redsum[tid >> 6] = lsum;
    __syncthreads();
    float inv = 1.f / (redsum[0] + redsum[1] + redsum[2] + redsum[3]);

    int d = tid & 63, ch = tid >> 6;
    float acc = 0.f;
    for (int k = ch; k < nk; k += 4)
        acc += sc[k] * qkv[(size_t)k * (3 * CC) + 2 * CC + h * HD + d];
    part[ch][d] = acc;
    __syncthreads();
    if (tid < HD) {
        float o = (part[0][tid] + part[1][tid] + part[2][tid] + part[3][tid]) * inv;
        atty[(size_t)q * CC + h * HD + tid] = o;
    }
}

// ---------------------------------------------------------------- MoE gating / routing
__global__ void zero_counts(int* counts) {
    if (threadIdx.x < EE) counts[threadIdx.x] = 0;
}

__global__ __launch_bounds__(64) void gate_kernel(const float* __restrict__ ln,
                                                  const float* __restrict__ gw,
                                                  int* __restrict__ topi, float* __restrict__ tsc,
                                                  int* __restrict__ counts) {
    int n = blockIdx.x;
    int lane = threadIdx.x;
    const float* xr = ln + (size_t)n * CC;
    float lg[EE];
#pragma unroll
    for (int e = 0; e < EE; e++) {
        const float* g = gw + e * CC;
        float p = 0.f;
#pragma unroll
        for (int i = 0; i < CC / 64; i++) {
            int c = i * 64 + lane;
            p += xr[c] * g[c];
        }
        for (int o = 32; o; o >>= 1) p += __shfl_xor(p, o);
        lg[e] = p;
    }
    if (lane == 0) {
        int b0 = 0; float v0 = lg[0];
        for (int e = 1; e < EE; e++) if (lg[e] > v0) { v0 = lg[e]; b0 = e; }
        int b1 = -1; float v1 = -1e30f;
        for (int e = 0; e < EE; e++) if (e != b0 && lg[e] > v1) { v1 = lg[e]; b1 = e; }
        float e1 = expf(v1 - v0);
        float den = 1.f + e1;
        topi[n * 2] = b0; topi[n * 2 + 1] = b1;
        tsc[n * 2] = 1.f / den; tsc[n * 2 + 1] = e1 / den;
        atomicAdd(&counts[b0], 1);
        atomicAdd(&counts[b1], 1);
    }
}

__global__ void offsets_kernel(const int* __restrict__ counts, int* __restrict__ offs,
                               int* __restrict__ cursor) {
    if (threadIdx.x == 0) {
        int o = 0;
        for (int e = 0; e < EE; e++) { offs[e] = o; o += counts[e]; cursor[e] = 0; }
    }
}

__global__ void scatter_kernel(const int* __restrict__ topi, int* __restrict__ cursor,
                               const int* __restrict__ offs, int* __restrict__ ptok,
                               int* __restrict__ ppos) {
    int n = blockIdx.x * 256 + threadIdx.x;
    if (n >= TT) return;
    for (int k = 0; k < KK2; k++) {
        int e = topi[n * 2 + k];
        int slot = atomicAdd(&cursor[e], 1);
        int p = offs[e] + slot;
        ptok[p] = n;
        ppos[n * 2 + k] = p;
    }
}

__global__ void combine_kernel(const float* __restrict__ ybuf, const float* __restrict__ tsc,
                               const int* __restrict__ ppos, float* __restrict__ x) {
    int i = blockIdx.x * 256 + threadIdx.x;
    if (i >= TT * CC) return;
    int n = i / CC, c = i % CC;
    float v = tsc[n * 2] * ybuf[(size_t)ppos[n * 2] * CC + c] +
              tsc[n * 2 + 1] * ybuf[(size_t)ppos[n * 2 + 1] * CC + c];
    x[i] += v;
}

// ---------------------------------------------------------------- lm head (wave per vocab row)
__global__ __launch_bounds__(256) void lm_head_kernel(const float* __restrict__ xr,
                                                      const float* __restrict__ wte,
                                                      float* __restrict__ out) {
    int row = blockIdx.x * 4 + (threadIdx.x >> 6);
    if (row >= VV) return;
    int lane = threadIdx.x & 63;
    const float* w = wte + (size_t)row * CC;
    float acc = 0.f;
#pragma unroll
    for (int i = 0; i < CC / 64; i++) {
        int c = i * 64 + lane;
        acc += xr[c] * w[c];
    }
    for (int o = 32; o; o >>= 1) acc += __shfl_xor(acc, o);
    if (lane == 0) out[row] = acc;
}

// ---------------------------------------------------------------- launch
extern "C" void kernel_launch(void* const* d_in, const int* in_sizes, int n_in,
                              void* d_out, int out_size, void* d_ws, size_t ws_size,
                              hipStream_t stream) {
    const int*   idx    = (const int*)d_in[0];
    const float* wte    = (const float*)d_in[1];
    const float* wpe    = (const float*)d_in[2];
    const float* ln1_g  = (const float*)d_in[3];
    const float* qkv_w  = (const float*)d_in[4];
    const float* proj_w = (const float*)d_in[5];
    const float* ln2_g  = (const float*)d_in[6];
    const float* gate_w = (const float*)d_in[7];
    const float* w1     = (const float*)d_in[8];
    const float* w2     = (const float*)d_in[9];
    const float* lnf_g  = (const float*)d_in[10];
    float* out = (float*)d_out;

    float* ws   = (float*)d_ws;
    float* x    = ws;                       // T*C
    float* ln   = x + TT * CC;              // T*C
    float* qkv  = ln + TT * CC;             // T*3C
    float* atty = qkv + (size_t)TT * 3 * CC;  // T*C
    float* hbuf = atty + TT * CC;           // NPAIR*F
    float* ybuf = hbuf + (size_t)NPAIR * FF;  // NPAIR*C
    float* tsc  = ybuf + (size_t)NPAIR * CC;  // T*K
    int* ibase  = (int*)(tsc + TT * KK2);
    int* topi   = ibase;                    // T*K
    int* ppos   = topi + TT * KK2;          // T*K
    int* ptok   = ppos + TT * KK2;          // NPAIR
    int* counts = ptok + NPAIR;             // E
    int* offs   = counts + EE;              // E
    int* cursor = offs + EE;                // E

    embed_kernel<<<(TT * CC + 255) / 256, 256, 0, stream>>>(idx, wte, wpe, x);

    for (int l = 0; l < LL; l++) {
        // attention block
        ln_kernel<<<TT, 256, 0, stream>>>(x, ln1_g + l * CC, ln, TT);
        gemm_mfma<0, 0, 0><<<dim3(3 * CC / 128, TT / 128, 1), 256, 0, stream>>>(
            ln, CC, qkv_w + (size_t)l * 3 * CC * CC, qkv, 3 * CC,
            nullptr, nullptr, nullptr, nullptr, TT, 3 * CC, CC);
        attn_kernel<<<dim3(TT, HH), 256, 0, stream>>>(qkv, atty);
        gemm_mfma<0, 0, 1><<<dim3(CC / 128, TT / 128, 1), 256, 0, stream>>>(
            atty, CC, proj_w + (size_t)l * CC * CC, x, CC,
            x, nullptr, nullptr, nullptr, TT, CC, CC);

        // MoE block
        ln_kernel<<<TT, 256, 0, stream>>>(x, ln2_g + l * CC, ln, TT);
        zero_counts<<<1, 32, 0, stream>>>(counts);
        gate_kernel<<<TT, 64, 0, stream>>>(ln, gate_w + (size_t)l * EE * CC, topi, tsc, counts);
        offsets_kernel<<<1, 32, 0, stream>>>(counts, offs, cursor);
        scatter_kernel<<<(TT + 255) / 256, 256, 0, stream>>>(topi, cursor, offs, ptok, ppos);
        gemm_mfma<1, 1, 0><<<dim3(FF / 128, TT / 128, EE), 256, 0, stream>>>(
            ln, CC, w1 + (size_t)l * EE * FF * CC, hbuf, FF,
            nullptr, ptok, offs, counts, 0, FF, CC);
        gemm_mfma<0, 0, 0><<<dim3(CC / 128, TT / 128, EE), 256, 0, stream>>>(
            hbuf, FF, w2 + (size_t)l * EE * CC * FF, ybuf, CC,
            nullptr, nullptr, offs, counts, 0, CC, FF);
        combine_kernel<<<(TT * CC + 255) / 256, 256, 0, stream>>>(ybuf, tsc, ppos, x);
    }

    // final LN (only the last position matters for the output)
    ln_kernel<<<1, 256, 0, stream>>>(x + (size_t)(TT - 1) * CC, lnf_g, ln, 1);
    lm_head_kernel<<<(VV + 3) / 4, 256, 0, stream>>>(ln, wte, out);
}